// Round 1
// 206.722 us; speedup vs baseline: 1.0628x; 1.0628x over previous
//
#include <hip/hip_runtime.h>
#include <hip/hip_bf16.h>

#define CM 256
#define CZ 128
#define CH 32
#define SS 128
#define NN 384

typedef short bf16x8 __attribute__((ext_vector_type(8)));
typedef float f32x4 __attribute__((ext_vector_type(4)));
typedef unsigned short us4 __attribute__((ext_vector_type(4)));
typedef unsigned short us8 __attribute__((ext_vector_type(8)));

__device__ __forceinline__ unsigned short f2bf(float f) {
    __hip_bfloat16 h = __float2bfloat16(f);
    return __builtin_bit_cast(unsigned short, h);
}

// ---------------- K0: weight prep ----------------
// WoF: fragment-linear Wo for k2 phase-2 direct loads:
//   WoF[(((cch*8)+zb)*64 + l)*8 + e] = Wo[(cch*32 + (l>>4)*8 + e)][zb*16 + (l&15)]
// WT = [WlT(32x256) | WrT(32x256)]
__global__ __launch_bounds__(256) void k0_transpose(
    const float* __restrict__ Wo, const float* __restrict__ Wl, const float* __restrict__ Wr,
    unsigned short* __restrict__ WoF, unsigned short* __restrict__ WT) {
    int n = blockIdx.x;  // 0..127
    int base = n * 1024;
#pragma unroll
    for (int u = 0; u < 4; u++) {
        int w   = base + u * 256 + threadIdx.x;   // 0..131071
        int e   = w & 7;
        int l   = (w >> 3) & 63;
        int zb  = (w >> 9) & 7;
        int cch = w >> 12;
        WoF[w] = f2bf(Wo[(size_t)(cch * 32 + (l >> 4) * 8 + e) * CZ + zb * 16 + (l & 15)]);
    }
    int k = threadIdx.x;  // blockDim == 256 == CM
    if (n < 32) {
        WT[n * CM + k] = f2bf(Wl[(size_t)k * CH + n]);
    } else if (n < 64) {
        WT[32 * CM + (n - 32) * CM + k] = f2bf(Wr[(size_t)k * CH + (n - 32)]);
    }
}

// ---------------- K1: LayerNorm + projections. Block = (i, s-half of 64). 256 thr, 2 blocks/CU ----------------
// Lt[(i*32+c)][s] = (LN(msa) @ Wl + bl)[s,i,c] / 128 ; Rt[(i*32+d)][s] = (... @ Wr + br)
__global__ __launch_bounds__(256, 2) void k1_ln_proj(
    const float* __restrict__ msa, const float* __restrict__ g, const float* __restrict__ bta,
    const unsigned short* __restrict__ WT, const float* __restrict__ bl, const float* __restrict__ br,
    unsigned short* __restrict__ Lt, unsigned short* __restrict__ Rt)
{
    __shared__ unsigned short A_lds[64 * 264];  // [s-local][k=0..255], +8 pad
    __shared__ unsigned short B_lds[64 * 264];  // [n][k] (n<32: Wl col, else Wr col)

    const int i    = blockIdx.x;
    const int sh   = blockIdx.y;        // s-half: 0 or 1
    const int t    = threadIdx.x;
    const int wv   = t >> 6;            // 0..3
    const int lane = t & 63;
    const int lr   = lane & 15, lg = lane >> 4;

    // --- LN: wave w handles local rows w*16..+15; lane covers 4 consecutive channels ---
    const float4 gv = ((const float4*)g)[lane];
    const float4 bv = ((const float4*)bta)[lane];
#pragma unroll 4
    for (int r = 0; r < 16; r++) {
        int sl = wv * 16 + r;
        int s  = sh * 64 + sl;
        float4 v = ((const float4*)(msa + ((size_t)s * NN + i) * CM))[lane];
        float sum = v.x + v.y + v.z + v.w;
        float sq  = v.x * v.x + v.y * v.y + v.z * v.z + v.w * v.w;
#pragma unroll
        for (int off = 32; off >= 1; off >>= 1) {
            sum += __shfl_xor(sum, off, 64);
            sq  += __shfl_xor(sq, off, 64);
        }
        float mu = sum * (1.f / CM);
        float rs = rsqrtf(sq * (1.f / CM) - mu * mu + 1e-5f);
        us4 pk;
        pk[0] = f2bf((v.x - mu) * rs * gv.x + bv.x);
        pk[1] = f2bf((v.y - mu) * rs * gv.y + bv.y);
        pk[2] = f2bf((v.z - mu) * rs * gv.z + bv.z);
        pk[3] = f2bf((v.w - mu) * rs * gv.w + bv.w);
        *(us4*)&A_lds[sl * 264 + lane * 4] = pk;
    }
    // --- W staging: pure us8 copies from pre-transposed WT ---
#pragma unroll
    for (int u = 0; u < 8; u++) {
        int id = u * 256 + t;            // 0..2047 us8 chunks; row = id>>5, kc = id&31
        *(us8*)&B_lds[(id >> 5) * 264 + (id & 31) * 8] = *(const us8*)&WT[id * 8];
    }
    __syncthreads();

    // --- MFMA: M=64(s) x N=64 x K=256; wave tile 32x32 ---
    const int m0 = (wv >> 1) * 32;
    const int n0 = (wv & 1) * 32;
    f32x4 acc[2][2];
#pragma unroll
    for (int a = 0; a < 2; a++)
#pragma unroll
        for (int b = 0; b < 2; b++) acc[a][b] = (f32x4){0.f, 0.f, 0.f, 0.f};

#pragma unroll
    for (int ks = 0; ks < 8; ks++) {
        int ko = ks * 32 + lg * 8;
        bf16x8 a0 = *(const bf16x8*)&A_lds[(m0 + lr) * 264 + ko];
        bf16x8 a1 = *(const bf16x8*)&A_lds[(m0 + 16 + lr) * 264 + ko];
        bf16x8 b0 = *(const bf16x8*)&B_lds[(n0 + lr) * 264 + ko];
        bf16x8 b1 = *(const bf16x8*)&B_lds[(n0 + 16 + lr) * 264 + ko];
        acc[0][0] = __builtin_amdgcn_mfma_f32_16x16x32_bf16(a0, b0, acc[0][0], 0, 0, 0);
        acc[0][1] = __builtin_amdgcn_mfma_f32_16x16x32_bf16(a0, b1, acc[0][1], 0, 0, 0);
        acc[1][0] = __builtin_amdgcn_mfma_f32_16x16x32_bf16(a1, b0, acc[1][0], 0, 0, 0);
        acc[1][1] = __builtin_amdgcn_mfma_f32_16x16x32_bf16(a1, b1, acc[1][1], 0, 0, 0);
    }

    // --- epilogue: C[m=s][n=ch] -> (Lt|Rt)[(i*32+ch)][s] ---
    const bool isL = (n0 == 0);   // wave-uniform
    const float scale = isL ? 0.0078125f : 1.f;   // 1/128 folded into left
#pragma unroll
    for (int mt = 0; mt < 2; mt++)
#pragma unroll
        for (int nt = 0; nt < 2; nt++) {
            int ch = (n0 + nt * 16 + lr) & 31;
            float bias = isL ? bl[ch] : br[ch];
            us4 pk;
#pragma unroll
            for (int rg = 0; rg < 4; rg++)
                pk[rg] = f2bf((acc[mt][nt][rg] + bias) * scale);
            unsigned short* dst = (isL ? Lt : Rt) + (size_t)(i * CH + ch) * SS
                                  + sh * 64 + m0 + mt * 16 + lg * 4;
            *(us4*)dst = pk;
        }
}

// ---------------- K2: fused GEMM1 (outer) + GEMM2 (@Wo) ----------------
// LDS plan (139264 = 136 KiB):
//   phase 1 : A [0,69632)  B [69632,139264)
//   phase 2 : Oh0 [0,65536)  Oh1 [65536,131072)   (Wo comes straight from L2 via WoF)
//   reduce  : RB f32 [0,139264)
#define TI 8
#define TJ 8
#define P1_B_OFF 69632     // 256*136*2
#define OH1_OFF  65536
#define K2_LDS   139264

__global__ __launch_bounds__(512, 2) void k2_fused(
    const unsigned short* __restrict__ Lt, const unsigned short* __restrict__ Rt,
    const unsigned short* __restrict__ WoF, const float* __restrict__ bo,
    float* __restrict__ out)
{
    extern __shared__ char smem[];
    unsigned short* A = (unsigned short*)(smem);             // [256][136]
    unsigned short* B = (unsigned short*)(smem + P1_B_OFF);  // [256][136]

    const int i0 = blockIdx.x * TI;
    const int j0 = blockIdx.y * TJ;
    const int t  = threadIdx.x;
    const int wv = t >> 6, lane = t & 63;
    const int lr = lane & 15, lg = lane >> 4;

    // ---- Phase 1 staging ----
    const unsigned short* gA = Lt + (size_t)i0 * CH * SS;
    const unsigned short* gB = Rt + (size_t)j0 * CH * SS;
#pragma unroll
    for (int it = 0; it < 8; it++) {
        int c  = it * 512 + t;
        int rw = c >> 4, kc = c & 15;
        *(us8*)(A + rw * 136 + kc * 8) = *(const us8*)(gA + rw * 128 + kc * 8);
        *(us8*)(B + rw * 136 + kc * 8) = *(const us8*)(gB + rw * 128 + kc * 8);
    }
    __syncthreads();

    // ---- Phase 1 compute: 256x256x128, wave tile 128x64, OPERANDS SWAPPED ----
    // acc element (lane,rg): O[rowA = m0+mt*16+lr][colB = n0w+nt*16+lg*4+rg]
    const int m0  = (wv >> 2) * 128;
    const int n0w = (wv & 3) * 64;

    f32x4 accE[4][4], accO[4][4];   // mt even (h=0) / mt odd (h=1)
#pragma unroll
    for (int a = 0; a < 4; a++)
#pragma unroll
        for (int b = 0; b < 4; b++) {
            accE[a][b] = (f32x4){0.f, 0.f, 0.f, 0.f};
            accO[a][b] = (f32x4){0.f, 0.f, 0.f, 0.f};
        }

#pragma unroll
    for (int ks = 0; ks < 4; ks++) {
        int ko = ks * 32 + lg * 8;
        bf16x8 af[8], bfr[4];
#pragma unroll
        for (int mt = 0; mt < 8; mt++) af[mt]  = *(const bf16x8*)(A + (m0 + mt * 16 + lr) * 136 + ko);
#pragma unroll
        for (int nt = 0; nt < 4; nt++) bfr[nt] = *(const bf16x8*)(B + (n0w + nt * 16 + lr) * 136 + ko);
#pragma unroll
        for (int mt = 0; mt < 8; mt++)
#pragma unroll
            for (int nt = 0; nt < 4; nt++) {
                if (mt & 1)
                    accO[mt >> 1][nt] = __builtin_amdgcn_mfma_f32_16x16x32_bf16(bfr[nt], af[mt], accO[mt >> 1][nt], 0, 0, 0);
                else
                    accE[mt >> 1][nt] = __builtin_amdgcn_mfma_f32_16x16x32_bf16(bfr[nt], af[mt], accE[mt >> 1][nt], 0, 0, 0);
            }
    }
    __syncthreads();   // A/B reads complete; LDS repurposed

    // ---- Wave role for phase 2 ----
    const int zsl = wv & 1, ksl = wv >> 1;

    // ---- Prefetch first Wo fragment set (cch = ksl) straight from L2 ----
    // (latency hidden behind O dump)
    bf16x8 wcur[4], wnxt[4];
#pragma unroll
    for (int bi = 0; bi < 4; bi++)
        wcur[bi] = *(const bf16x8*)&WoF[(((size_t)ksl * 8 + zsl * 4 + bi) * 64 + lane) * 8];

    // ---- Dump BOTH O halves with b64 packed writes ----
    // Oh[h][rowH=ii*16+lr][col], okey = (rowH ^ (rowH>>4)) & 7, chk = (col>>3)^okey
    {
        unsigned short* Oh0 = (unsigned short*)smem;
        unsigned short* Oh1 = (unsigned short*)(smem + OH1_OFF);
#pragma unroll
        for (int mh = 0; mh < 4; mh++) {
            int iiw  = (wv >> 2) * 4 + mh;
            int rowH = iiw * 16 + lr;
            int okey = (rowH ^ (rowH >> 4)) & 7;
#pragma unroll
            for (int nt = 0; nt < 4; nt++) {
                int colBase = n0w + nt * 16 + lg * 4;     // + rg (0..3), no octet carry
                int chk = (colBase >> 3) ^ okey;
                int off = rowH * 256 + chk * 8 + (lg & 1) * 4;
                us4 pkE, pkO;
#pragma unroll
                for (int rg = 0; rg < 4; rg++) {
                    pkE[rg] = f2bf(accE[mh][nt][rg]);
                    pkO[rg] = f2bf(accO[mh][nt][rg]);
                }
                *(us4*)&Oh0[off] = pkE;
                *(us4*)&Oh1[off] = pkO;
            }
        }
    }
    __syncthreads();   // O dump visible to all waves

    // ---- Phase 2: out[pair=64][z=128] = O[64][1024] @ WoF, BARRIER-FREE ----
    // Wave (zsl,ksl) handles K-slices cch = c*4+ksl, z-half zsl; Wo fragments
    // come straight from L2 (each byte consumed exactly once per block, so LDS
    // staging was pure overhead). Register double-buffer one chunk ahead.
    f32x4 acc2[4][4];
#pragma unroll
    for (int a = 0; a < 4; a++)
#pragma unroll
        for (int b = 0; b < 4; b++) acc2[a][b] = (f32x4){0.f, 0.f, 0.f, 0.f};

#pragma unroll
    for (int c = 0; c < 8; c++) {
        if (c < 7) {
            int cchn = (c + 1) * 4 + ksl;
#pragma unroll
            for (int bi = 0; bi < 4; bi++)
                wnxt[bi] = *(const bf16x8*)&WoF[(((size_t)cchn * 8 + zsl * 4 + bi) * 64 + lane) * 8];
        }

        const int cch = c * 4 + ksl;           // 0..31
        const int hh  = cch >> 4;
        const int cH  = cch & 15;
        const unsigned short* OhX = (const unsigned short*)(smem + (hh ? OH1_OFF : 0));

        bf16x8 af2[4];
#pragma unroll
        for (int ai = 0; ai < 4; ai++) {
            int rowH = (ai * 2 + ((lane >> 3) & 1)) * 16 + cH;
            int okey = (rowH ^ (rowH >> 4)) & 7;
            int chk  = (((lane & 7) * 4 + lg) ^ okey);
            af2[ai] = *(const bf16x8*)&OhX[rowH * 256 + chk * 8];
        }
#pragma unroll
        for (int ai = 0; ai < 4; ai++)
#pragma unroll
            for (int bi = 0; bi < 4; bi++)
                acc2[ai][bi] = __builtin_amdgcn_mfma_f32_16x16x32_bf16(af2[ai], wcur[bi], acc2[ai][bi], 0, 0, 0);

        if (c < 7) {
#pragma unroll
            for (int bi = 0; bi < 4; bi++) wcur[bi] = wnxt[bi];
        }
    }
    __syncthreads();   // O reads done; LDS -> reduction buffer

    // ---- K-slot reduction: RB[4 ks][128 z][68 pair-stride] f32 ----
    float* RB = (float*)smem;
#pragma unroll
    for (int ai = 0; ai < 4; ai++)
#pragma unroll
        for (int bi = 0; bi < 4; bi++) {
            int z  = zsl * 64 + bi * 16 + lr;
            int pr = ai * 16 + lg * 4;
            *(f32x4*)&RB[ksl * 8704 + z * 68 + pr] = acc2[ai][bi];
        }
    __syncthreads();

    {
        int z = t >> 2, pq = t & 3;
        float bz = bo[z];
#pragma unroll
        for (int u = 0; u < 4; u++) {
            int p0r = pq * 16 + u * 4;
            f32x4 s = (f32x4){0.f, 0.f, 0.f, 0.f};
#pragma unroll
            for (int ks2 = 0; ks2 < 4; ks2++)
                s += *(const f32x4*)&RB[ks2 * 8704 + z * 68 + p0r];
#pragma unroll
            for (int e = 0; e < 4; e++) {
                int p = p0r + e;
                out[((size_t)(i0 + (p >> 3)) * NN + (j0 + (p & 7))) * CZ + z] = s[e] + bz;
            }
        }
    }
}

extern "C" void kernel_launch(void* const* d_in, const int* in_sizes, int n_in,
                              void* d_out, int out_size, void* d_ws, size_t ws_size,
                              hipStream_t stream) {
    const float* msa  = (const float*)d_in[0];
    const float* ln_g = (const float*)d_in[1];
    const float* ln_b = (const float*)d_in[2];
    const float* Wl   = (const float*)d_in[3];
    const float* bl   = (const float*)d_in[4];
    const float* Wr   = (const float*)d_in[5];
    const float* br   = (const float*)d_in[6];
    const float* Wo   = (const float*)d_in[7];
    const float* bo   = (const float*)d_in[8];
    float* out = (float*)d_out;

    unsigned short* Lt  = (unsigned short*)d_ws;                 // [12288][128] bf16
    unsigned short* Rt  = Lt + (size_t)NN * CH * SS;             // [12288][128] bf16
    unsigned short* WoF = Rt + (size_t)NN * CH * SS;             // [32][8][64][8] bf16 fragment-linear
    unsigned short* WT  = WoF + (size_t)CZ * CH * CH;            // [64][256] bf16 (WlT|WrT)

    hipFuncSetAttribute((const void*)k2_fused,
                        hipFuncAttributeMaxDynamicSharedMemorySize, K2_LDS);

    k0_transpose<<<dim3(CZ), dim3(256), 0, stream>>>(Wo, Wl, Wr, WoF, WT);
    k1_ln_proj<<<dim3(NN, 2), dim3(256), 0, stream>>>(msa, ln_g, ln_b, WT, bl, br, Lt, Rt);
    k2_fused<<<dim3(NN / TI, NN / TJ), dim3(512), K2_LDS, stream>>>(Lt, Rt, WoF, bo, out);
}

// Round 2
// 203.059 us; speedup vs baseline: 1.0820x; 1.0180x over previous
//
#include <hip/hip_runtime.h>
#include <hip/hip_bf16.h>

#define CM 256
#define CZ 128
#define CH 32
#define SS 128
#define NN 384

typedef short bf16x8 __attribute__((ext_vector_type(8)));
typedef float f32x4 __attribute__((ext_vector_type(4)));
typedef unsigned short us4 __attribute__((ext_vector_type(4)));
typedef unsigned short us8 __attribute__((ext_vector_type(8)));

__device__ __forceinline__ unsigned short f2bf(float f) {
    __hip_bfloat16 h = __float2bfloat16(f);
    return __builtin_bit_cast(unsigned short, h);
}

// async 16B global -> LDS (dest = wave-uniform base + lane*16)
__device__ __forceinline__ void gl_lds16(const unsigned short* g, unsigned short* l) {
    __builtin_amdgcn_global_load_lds(
        (const __attribute__((address_space(1))) unsigned int*)g,
        (__attribute__((address_space(3))) unsigned int*)l,
        16, 0, 0);
}

// ---------------- K0: weight prep ----------------
// WoF: fragment-linear Wo for k2 phase-2 direct loads:
//   WoF[(((cch*8)+zb)*64 + l)*8 + e] = Wo[(cch*32 + (l>>4)*8 + e)][zb*16 + (l&15)]
// WT = [WlT(32x256) | WrT(32x256)]
__global__ __launch_bounds__(256) void k0_transpose(
    const float* __restrict__ Wo, const float* __restrict__ Wl, const float* __restrict__ Wr,
    unsigned short* __restrict__ WoF, unsigned short* __restrict__ WT) {
    int n = blockIdx.x;  // 0..127
    int base = n * 1024;
#pragma unroll
    for (int u = 0; u < 4; u++) {
        int w   = base + u * 256 + threadIdx.x;   // 0..131071
        int e   = w & 7;
        int l   = (w >> 3) & 63;
        int zb  = (w >> 9) & 7;
        int cch = w >> 12;
        WoF[w] = f2bf(Wo[(size_t)(cch * 32 + (l >> 4) * 8 + e) * CZ + zb * 16 + (l & 15)]);
    }
    int k = threadIdx.x;  // blockDim == 256 == CM
    if (n < 32) {
        WT[n * CM + k] = f2bf(Wl[(size_t)k * CH + n]);
    } else if (n < 64) {
        WT[32 * CM + (n - 32) * CM + k] = f2bf(Wr[(size_t)k * CH + (n - 32)]);
    }
}

// ---------------- K1: LayerNorm + projections. Block = (i, s-half of 64). 256 thr, 2 blocks/CU ----------------
__global__ __launch_bounds__(256, 2) void k1_ln_proj(
    const float* __restrict__ msa, const float* __restrict__ g, const float* __restrict__ bta,
    const unsigned short* __restrict__ WT, const float* __restrict__ bl, const float* __restrict__ br,
    unsigned short* __restrict__ Lt, unsigned short* __restrict__ Rt)
{
    __shared__ unsigned short A_lds[64 * 264];
    __shared__ unsigned short B_lds[64 * 264];

    const int i    = blockIdx.x;
    const int sh   = blockIdx.y;
    const int t    = threadIdx.x;
    const int wv   = t >> 6;
    const int lane = t & 63;
    const int lr   = lane & 15, lg = lane >> 4;

    const float4 gv = ((const float4*)g)[lane];
    const float4 bv = ((const float4*)bta)[lane];
#pragma unroll 4
    for (int r = 0; r < 16; r++) {
        int sl = wv * 16 + r;
        int s  = sh * 64 + sl;
        float4 v = ((const float4*)(msa + ((size_t)s * NN + i) * CM))[lane];
        float sum = v.x + v.y + v.z + v.w;
        float sq  = v.x * v.x + v.y * v.y + v.z * v.z + v.w * v.w;
#pragma unroll
        for (int off = 32; off >= 1; off >>= 1) {
            sum += __shfl_xor(sum, off, 64);
            sq  += __shfl_xor(sq, off, 64);
        }
        float mu = sum * (1.f / CM);
        float rs = rsqrtf(sq * (1.f / CM) - mu * mu + 1e-5f);
        us4 pk;
        pk[0] = f2bf((v.x - mu) * rs * gv.x + bv.x);
        pk[1] = f2bf((v.y - mu) * rs * gv.y + bv.y);
        pk[2] = f2bf((v.z - mu) * rs * gv.z + bv.z);
        pk[3] = f2bf((v.w - mu) * rs * gv.w + bv.w);
        *(us4*)&A_lds[sl * 264 + lane * 4] = pk;
    }
#pragma unroll
    for (int u = 0; u < 8; u++) {
        int id = u * 256 + t;
        *(us8*)&B_lds[(id >> 5) * 264 + (id & 31) * 8] = *(const us8*)&WT[id * 8];
    }
    __syncthreads();

    const int m0 = (wv >> 1) * 32;
    const int n0 = (wv & 1) * 32;
    f32x4 acc[2][2];
#pragma unroll
    for (int a = 0; a < 2; a++)
#pragma unroll
        for (int b = 0; b < 2; b++) acc[a][b] = (f32x4){0.f, 0.f, 0.f, 0.f};

#pragma unroll
    for (int ks = 0; ks < 8; ks++) {
        int ko = ks * 32 + lg * 8;
        bf16x8 a0 = *(const bf16x8*)&A_lds[(m0 + lr) * 264 + ko];
        bf16x8 a1 = *(const bf16x8*)&A_lds[(m0 + 16 + lr) * 264 + ko];
        bf16x8 b0 = *(const bf16x8*)&B_lds[(n0 + lr) * 264 + ko];
        bf16x8 b1 = *(const bf16x8*)&B_lds[(n0 + 16 + lr) * 264 + ko];
        acc[0][0] = __builtin_amdgcn_mfma_f32_16x16x32_bf16(a0, b0, acc[0][0], 0, 0, 0);
        acc[0][1] = __builtin_amdgcn_mfma_f32_16x16x32_bf16(a0, b1, acc[0][1], 0, 0, 0);
        acc[1][0] = __builtin_amdgcn_mfma_f32_16x16x32_bf16(a1, b0, acc[1][0], 0, 0, 0);
        acc[1][1] = __builtin_amdgcn_mfma_f32_16x16x32_bf16(a1, b1, acc[1][1], 0, 0, 0);
    }

    const bool isL = (n0 == 0);
    const float scale = isL ? 0.0078125f : 1.f;
#pragma unroll
    for (int mt = 0; mt < 2; mt++)
#pragma unroll
        for (int nt = 0; nt < 2; nt++) {
            int ch = (n0 + nt * 16 + lr) & 31;
            float bias = isL ? bl[ch] : br[ch];
            us4 pk;
#pragma unroll
            for (int rg = 0; rg < 4; rg++)
                pk[rg] = f2bf((acc[mt][nt][rg] + bias) * scale);
            unsigned short* dst = (isL ? Lt : Rt) + (size_t)(i * CH + ch) * SS
                                  + sh * 64 + m0 + mt * 16 + lg * 4;
            *(us4*)dst = pk;
        }
}

// ---------------- K2: fused GEMM1 (outer) + GEMM2 (@Wo) ----------------
// LDS plan (139264 bytes):
//   phase 1 : A [0,65536)  B [65536,131072)
//             each split in K-half planes of 32KB; element (row,k):
//             plane(k>>6) + row*64 + ((((k>>3)&7) ^ (row&7))*8 + (k&7))  [shorts]
//   phase 2 : Oh0 [0,65536)  Oh1 [65536,131072)  (Wo direct from L2 via WoF)
//   reduce  : RB f32 [0,139264)
#define TI 8
#define TJ 8
#define P1_B_OFF 65536
#define OH1_OFF  65536
#define K2_LDS   139264

// fragment read: o = k-octet index 0..15
#define FRAG(base, row, o) \
    (*(const bf16x8*)((base) + (((o) & 8) << 11) + (row) * 64 + ((((o) & 7) ^ ((row) & 7)) << 3)))

__global__ __launch_bounds__(512, 2) void k2_fused(
    const unsigned short* __restrict__ Lt, const unsigned short* __restrict__ Rt,
    const unsigned short* __restrict__ WoF, const float* __restrict__ bo,
    float* __restrict__ out)
{
    extern __shared__ char smem[];
    unsigned short* A = (unsigned short*)(smem);             // planes [2][256][64]
    unsigned short* B = (unsigned short*)(smem + P1_B_OFF);  // planes [2][256][64]

    const int i0 = blockIdx.x * TI;
    const int j0 = blockIdx.y * TJ;
    const int t  = threadIdx.x;
    const int wv = t >> 6, lane = t & 63;
    const int lr = lane & 15, lg = lane >> 4;

    const unsigned short* gA = Lt + (size_t)i0 * CH * SS;
    const unsigned short* gB = Rt + (size_t)j0 * CH * SS;

    // ---- Phase 1 staging: async global->LDS; XOR applied on SOURCE, LDS dest linear ----
    // wave-op q covers LDS octets q*64..q*64+63 of the plane (8 rows x 8 octets)
    auto stage_half = [&](const unsigned short* gS, unsigned short* lS, int h) {
#pragma unroll
        for (int p = 0; p < 4; p++) {
            int q = wv * 4 + p;
            int d = q * 64 + lane;
            int row = d >> 3, ow = d & 7;
            const unsigned short* src = gS + row * 128 + (h * 8 + (ow ^ (row & 7))) * 8;
            gl_lds16(src, lS + h * 16384 + q * 512);
        }
    };

    stage_half(gA, A, 0);
    stage_half(gB, B, 0);
    asm volatile("s_waitcnt vmcnt(0)" ::: "memory");
    __syncthreads();
    // half 1 in flight under half-0 compute
    stage_half(gA, A, 1);
    stage_half(gB, B, 1);

    // ---- Phase 1 compute: 256x256x128, wave tile 128x64, operands swapped ----
    const int m0  = (wv >> 2) * 128;
    const int n0w = (wv & 3) * 64;

    f32x4 accE[4][4], accO[4][4];
#pragma unroll
    for (int a = 0; a < 4; a++)
#pragma unroll
        for (int b = 0; b < 4; b++) {
            accE[a][b] = (f32x4){0.f, 0.f, 0.f, 0.f};
            accO[a][b] = (f32x4){0.f, 0.f, 0.f, 0.f};
        }

#pragma unroll
    for (int ks = 0; ks < 2; ks++) {
        int o = ks * 4 + lg;
        bf16x8 af[8], bfr[4];
#pragma unroll
        for (int mt = 0; mt < 8; mt++) af[mt]  = FRAG(A, m0 + mt * 16 + lr, o);
#pragma unroll
        for (int nt = 0; nt < 4; nt++) bfr[nt] = FRAG(B, n0w + nt * 16 + lr, o);
#pragma unroll
        for (int mt = 0; mt < 8; mt++)
#pragma unroll
            for (int nt = 0; nt < 4; nt++) {
                if (mt & 1)
                    accO[mt >> 1][nt] = __builtin_amdgcn_mfma_f32_16x16x32_bf16(bfr[nt], af[mt], accO[mt >> 1][nt], 0, 0, 0);
                else
                    accE[mt >> 1][nt] = __builtin_amdgcn_mfma_f32_16x16x32_bf16(bfr[nt], af[mt], accE[mt >> 1][nt], 0, 0, 0);
            }
    }
    asm volatile("s_waitcnt vmcnt(0)" ::: "memory");
    __syncthreads();   // half 1 landed
#pragma unroll
    for (int ks = 2; ks < 4; ks++) {
        int o = ks * 4 + lg;
        bf16x8 af[8], bfr[4];
#pragma unroll
        for (int mt = 0; mt < 8; mt++) af[mt]  = FRAG(A, m0 + mt * 16 + lr, o);
#pragma unroll
        for (int nt = 0; nt < 4; nt++) bfr[nt] = FRAG(B, n0w + nt * 16 + lr, o);
#pragma unroll
        for (int mt = 0; mt < 8; mt++)
#pragma unroll
            for (int nt = 0; nt < 4; nt++) {
                if (mt & 1)
                    accO[mt >> 1][nt] = __builtin_amdgcn_mfma_f32_16x16x32_bf16(bfr[nt], af[mt], accO[mt >> 1][nt], 0, 0, 0);
                else
                    accE[mt >> 1][nt] = __builtin_amdgcn_mfma_f32_16x16x32_bf16(bfr[nt], af[mt], accE[mt >> 1][nt], 0, 0, 0);
            }
    }
    __syncthreads();   // A/B reads complete; LDS repurposed

    // ---- Wave role for phase 2 ----
    const int zsl = wv & 1, ksl = wv >> 1;

    // ---- 2-deep Wo prefetch (chunks 0,1) straight from L2; latency hidden behind O dump ----
    bf16x8 wbuf[2][4];
#pragma unroll
    for (int bi = 0; bi < 4; bi++)
        wbuf[0][bi] = *(const bf16x8*)&WoF[(((size_t)(0 * 4 + ksl) * 8 + zsl * 4 + bi) * 64 + lane) * 8];
#pragma unroll
    for (int bi = 0; bi < 4; bi++)
        wbuf[1][bi] = *(const bf16x8*)&WoF[(((size_t)(1 * 4 + ksl) * 8 + zsl * 4 + bi) * 64 + lane) * 8];

    // ---- Dump BOTH O halves with b64 packed writes ----
    {
        unsigned short* Oh0 = (unsigned short*)smem;
        unsigned short* Oh1 = (unsigned short*)(smem + OH1_OFF);
#pragma unroll
        for (int mh = 0; mh < 4; mh++) {
            int iiw  = (wv >> 2) * 4 + mh;
            int rowH = iiw * 16 + lr;
            int okey = (rowH ^ (rowH >> 4)) & 7;
#pragma unroll
            for (int nt = 0; nt < 4; nt++) {
                int colBase = n0w + nt * 16 + lg * 4;
                int chk = (colBase >> 3) ^ okey;
                int off = rowH * 256 + chk * 8 + (lg & 1) * 4;
                us4 pkE, pkO;
#pragma unroll
                for (int rg = 0; rg < 4; rg++) {
                    pkE[rg] = f2bf(accE[mh][nt][rg]);
                    pkO[rg] = f2bf(accO[mh][nt][rg]);
                }
                *(us4*)&Oh0[off] = pkE;
                *(us4*)&Oh1[off] = pkO;
            }
        }
    }
    __syncthreads();   // O dump visible to all waves

    // ---- Phase 2: out[pair=64][z=128] = O[64][1024] @ WoF, barrier-free, 2-deep pipeline ----
    f32x4 acc2[4][4];
#pragma unroll
    for (int a = 0; a < 4; a++)
#pragma unroll
        for (int b = 0; b < 4; b++) acc2[a][b] = (f32x4){0.f, 0.f, 0.f, 0.f};

#pragma unroll
    for (int c = 0; c < 8; c++) {
        const int cch = c * 4 + ksl;           // 0..31
        const int hh  = cch >> 4;
        const int cH  = cch & 15;
        const unsigned short* OhX = (const unsigned short*)(smem + (hh ? OH1_OFF : 0));

        bf16x8 af2[4];
#pragma unroll
        for (int ai = 0; ai < 4; ai++) {
            int rowH = (ai * 2 + ((lane >> 3) & 1)) * 16 + cH;
            int okey = (rowH ^ (rowH >> 4)) & 7;
            int chk  = (((lane & 7) * 4 + lg) ^ okey);
            af2[ai] = *(const bf16x8*)&OhX[rowH * 256 + chk * 8];
        }
#pragma unroll
        for (int ai = 0; ai < 4; ai++)
#pragma unroll
            for (int bi = 0; bi < 4; bi++)
                acc2[ai][bi] = __builtin_amdgcn_mfma_f32_16x16x32_bf16(af2[ai], wbuf[c & 1][bi], acc2[ai][bi], 0, 0, 0);

        if (c < 6) {   // refill the slot just consumed with chunk c+2
            int cchn = (c + 2) * 4 + ksl;
#pragma unroll
            for (int bi = 0; bi < 4; bi++)
                wbuf[c & 1][bi] = *(const bf16x8*)&WoF[(((size_t)cchn * 8 + zsl * 4 + bi) * 64 + lane) * 8];
        }
    }
    __syncthreads();   // O reads done; LDS -> reduction buffer

    // ---- K-slot reduction: RB[4 ks][128 z][68 pair-stride] f32 ----
    float* RB = (float*)smem;
#pragma unroll
    for (int ai = 0; ai < 4; ai++)
#pragma unroll
        for (int bi = 0; bi < 4; bi++) {
            int z  = zsl * 64 + bi * 16 + lr;
            int pr = ai * 16 + lg * 4;
            *(f32x4*)&RB[ksl * 8704 + z * 68 + pr] = acc2[ai][bi];
        }
    __syncthreads();

    {
        int z = t >> 2, pq = t & 3;
        float bz = bo[z];
#pragma unroll
        for (int u = 0; u < 4; u++) {
            int p0r = pq * 16 + u * 4;
            f32x4 s = (f32x4){0.f, 0.f, 0.f, 0.f};
#pragma unroll
            for (int ks2 = 0; ks2 < 4; ks2++)
                s += *(const f32x4*)&RB[ks2 * 8704 + z * 68 + p0r];
#pragma unroll
            for (int e = 0; e < 4; e++) {
                int p = p0r + e;
                out[((size_t)(i0 + (p >> 3)) * NN + (j0 + (p & 7))) * CZ + z] = s[e] + bz;
            }
        }
    }
}

extern "C" void kernel_launch(void* const* d_in, const int* in_sizes, int n_in,
                              void* d_out, int out_size, void* d_ws, size_t ws_size,
                              hipStream_t stream) {
    const float* msa  = (const float*)d_in[0];
    const float* ln_g = (const float*)d_in[1];
    const float* ln_b = (const float*)d_in[2];
    const float* Wl   = (const float*)d_in[3];
    const float* bl   = (const float*)d_in[4];
    const float* Wr   = (const float*)d_in[5];
    const float* br   = (const float*)d_in[6];
    const float* Wo   = (const float*)d_in[7];
    const float* bo   = (const float*)d_in[8];
    float* out = (float*)d_out;

    unsigned short* Lt  = (unsigned short*)d_ws;                 // [12288][128] bf16
    unsigned short* Rt  = Lt + (size_t)NN * CH * SS;             // [12288][128] bf16
    unsigned short* WoF = Rt + (size_t)NN * CH * SS;             // [32][8][64][8] bf16 fragment-linear
    unsigned short* WT  = WoF + (size_t)CZ * CH * CH;            // [64][256] bf16 (WlT|WrT)

    hipFuncSetAttribute((const void*)k2_fused,
                        hipFuncAttributeMaxDynamicSharedMemorySize, K2_LDS);

    k0_transpose<<<dim3(CZ), dim3(256), 0, stream>>>(Wo, Wl, Wr, WoF, WT);
    k1_ln_proj<<<dim3(NN, 2), dim3(256), 0, stream>>>(msa, ln_g, ln_b, WT, bl, br, Lt, Rt);
    k2_fused<<<dim3(NN / TI, NN / TJ), dim3(512), K2_LDS, stream>>>(Lt, Rt, WoF, bo, out);
}